// Round 5
// baseline (756.404 us; speedup 1.0000x reference)
//
#include <hip/hip_runtime.h>
#include <hip/hip_fp16.h>
#include <stdint.h>
#include <stddef.h>

typedef float f32x4 __attribute__((ext_vector_type(4)));
typedef int   i32x8 __attribute__((ext_vector_type(8)));

#define GLOBAL_AS __attribute__((address_space(1)))
#define LDS_AS    __attribute__((address_space(3)))

__device__ __forceinline__ void gload_lds16(const void* g, void* l) {
    __builtin_amdgcn_global_load_lds((const GLOBAL_AS void*)g,
                                     (LDS_AS void*)l, 16, 0, 0);
}

// ---------------- fused amax (x -> scal[0], w -> scal[1]) ----------------
__global__ void amax2_kernel(const float* __restrict__ x, size_t nx4,
                             const float* __restrict__ w, size_t nw4,
                             float* __restrict__ scal, int xblocks, int wblocks) {
    int b = blockIdx.x;
    const float4* p4; size_t n4; float* out; int nb; int bb;
    if (b < xblocks) { p4 = (const float4*)x; n4 = nx4; out = scal;     nb = xblocks; bb = b; }
    else             { p4 = (const float4*)w; n4 = nw4; out = scal + 1; nb = wblocks; bb = b - xblocks; }
    float m = 0.f;
    for (size_t i = (size_t)bb * blockDim.x + threadIdx.x; i < n4;
         i += (size_t)nb * blockDim.x) {
        float4 v = p4[i];
        m = fmaxf(m, fmaxf(fmaxf(fabsf(v.x), fabsf(v.y)),
                           fmaxf(fabsf(v.z), fabsf(v.w))));
    }
    #pragma unroll
    for (int off = 32; off > 0; off >>= 1)
        m = fmaxf(m, __shfl_down(m, off, 64));
    __shared__ float sm[4];
    int wid = threadIdx.x >> 6;
    if ((threadIdx.x & 63) == 0) sm[wid] = m;
    __syncthreads();
    if (threadIdx.x == 0) {
        m = fmaxf(fmaxf(sm[0], sm[1]), fmaxf(sm[2], sm[3]));
        atomicMax((unsigned int*)out, __float_as_uint(m));
    }
}

// ---------------- fused fp8 e4m3 quantization (16 elems/thread) ----------------
__global__ void quant2_kernel(const float* __restrict__ x, const float* __restrict__ w,
                              const float* __restrict__ scal,
                              uint32_t* __restrict__ qx, uint32_t* __restrict__ qw,
                              int xblocks) {
    int b = blockIdx.x;
    const float* src; uint32_t* dst; float sc; size_t i;
    if (b < xblocks) { src = x; dst = qx; sc = 448.f / fmaxf(scal[0], 1e-12f);
                       i = (size_t)b * blockDim.x + threadIdx.x; }
    else             { src = w; dst = qw; sc = 448.f / fmaxf(scal[1], 1e-12f);
                       i = (size_t)(b - xblocks) * blockDim.x + threadIdx.x; }
    const float4* s4 = (const float4*)src + i * 4;
    uint32_t r[4];
    #pragma unroll
    for (int j = 0; j < 4; ++j) {
        float4 v = s4[j];
        uint32_t u = __builtin_amdgcn_cvt_pk_fp8_f32(v.x * sc, v.y * sc, 0u, false);
        u = __builtin_amdgcn_cvt_pk_fp8_f32(v.z * sc, v.w * sc, u, true);
        r[j] = u;
    }
    uint4 out; out.x = r[0]; out.y = r[1]; out.z = r[2]; out.w = r[3];
    *(uint4*)(dst + i * 4) = out;
}

// ------- MX-fp8 256x256 8-phase GEMM: C[M][N] = A[M][K] * B[N][K]^T -------
// vs round 4: removed lgkmcnt(0)+sched_barrier(0) pinning (reads are
// compiler-visible; dual barriers + counted vmcnt already fence buffer reuse)
// and moved staging addressing to 32-bit offsets -> kills register spills.
#define BM 256
#define BN 256
#define BKB 128   // K-bytes per tile

__global__ __launch_bounds__(512, 2) void gemm_mxfp8_8p(
    const uint8_t* __restrict__ Aq,   // [M][K] fp8
    const uint8_t* __restrict__ Bq,   // [N][K] fp8
    const float* __restrict__ scal,
    const float* __restrict__ bias,   // [N] f32 (fp16-exact values)
    float* __restrict__ C,            // [M][N] f32 (fp16-rounded values)
    int M, int N, int K)
{
    // [buf][op A=0/B=1][half][128 rows * 128 B] = 128 KiB
    __shared__ __align__(16) uint8_t lds[2][2][2][128 * 128];

    const int tid  = threadIdx.x;
    const int wid  = tid >> 6;
    const int lane = tid & 63;
    const int wm = wid >> 2;           // 0..1
    const int wn = wid & 3;            // 0..3
    const int r16 = lane & 15, hi = lane >> 4;

    // XCD-aware swizzle (nwg = 2048, %8 == 0)
    const int nwg = gridDim.x;
    const int cpx = nwg >> 3;
    const int sbid = (blockIdx.x & 7) * cpx + (blockIdx.x >> 3);
    const int nbn = N / BN;            // 32
    const int bn = sbid & (nbn - 1);
    const int bm = sbid / nbn;

    const uint8_t* Abase = Aq + (size_t)bm * BM * K;
    const uint8_t* Bbase = Bq + (size_t)bn * BN * K;

    // staging: per phase one half-tile (128 rows x 128 B), 2 x 16B per thread
    const int srow = tid >> 3;                                   // 0..63
    const uint32_t soff = (uint32_t)srow * (uint32_t)K +
                          (uint32_t)(((tid & 7) ^ (srow & 7)) << 4);

    // fragment-read swizzled chunk offsets (row & 7 == r16 & 7)
    const int swz = r16 & 7;
    const int u0 = ((hi * 2)     ^ swz) << 4;
    const int u1 = ((hi * 2 + 1) ^ swz) << 4;

#define STAGE(opbase, opi, bufi, h, s)                                            \
  { const uint8_t* g_ = (opbase) + (uint32_t)((h) * 128 * K + (s) * BKB) + soff;  \
    uint8_t* l_ = &lds[bufi][opi][h][tid * 16];                                   \
    gload_lds16(g_, l_);                                                          \
    gload_lds16(g_ + (uint32_t)(64 * K), l_ + 8192); }

#define LDA(bufc, g)                                                              \
  { const uint8_t* base_ = &lds[bufc][0][wm][0];                                  \
    _Pragma("unroll") for (int j_ = 0; j_ < 4; ++j_) {                            \
      const uint8_t* p_ = base_ + ((g) * 64 + j_ * 16 + r16) * 128;               \
      int4 q0_ = *(const int4*)(p_ + u0);                                         \
      int4 q1_ = *(const int4*)(p_ + u1);                                         \
      a[j_] = (i32x8){q0_.x, q0_.y, q0_.z, q0_.w, q1_.x, q1_.y, q1_.z, q1_.w}; } }

#define LDB(bufc, g)                                                              \
  { const uint8_t* base_ = &lds[bufc][1][wn >> 1][0];                             \
    _Pragma("unroll") for (int j_ = 0; j_ < 2; ++j_) {                            \
      const uint8_t* p_ = base_ + ((wn & 1) * 64 + ((g) * 2 + j_) * 16 + r16) * 128; \
      int4 q0_ = *(const int4*)(p_ + u0);                                         \
      int4 q1_ = *(const int4*)(p_ + u1);                                         \
      b[(g) * 2 + j_] = (i32x8){q0_.x, q0_.y, q0_.z, q0_.w, q1_.x, q1_.y, q1_.z, q1_.w}; } }

#define MMA(g_m, g_n)                                                             \
  __builtin_amdgcn_s_setprio(1);                                                  \
  _Pragma("unroll") for (int mi_ = 0; mi_ < 4; ++mi_)                             \
    _Pragma("unroll") for (int nj_ = 0; nj_ < 2; ++nj_)                           \
      acc[(g_m) * 4 + mi_][(g_n) * 2 + nj_] =                                     \
        __builtin_amdgcn_mfma_scale_f32_16x16x128_f8f6f4(                         \
          a[mi_], b[(g_n) * 2 + nj_], acc[(g_m) * 4 + mi_][(g_n) * 2 + nj_],      \
          0, 0, 0, 0x7F7F7F7F, 0, 0x7F7F7F7F);                                    \
  __builtin_amdgcn_s_setprio(0);

#define PH_BEGIN() __builtin_amdgcn_s_barrier()

#define PH_END() __builtin_amdgcn_s_barrier()

#define PH_END_VM(n) do { asm volatile("s_waitcnt vmcnt(" #n ")" ::: "memory");   \
    __builtin_amdgcn_s_barrier(); } while (0)

    f32x4 acc[8][4] = {};
    i32x8 a[4], b[4];

    // ---- prologue: stage t0 (all 4 halves) + t1.{Bh0, Ah0} ----
    STAGE(Abase, 0, 0, 0, 0);
    STAGE(Abase, 0, 0, 1, 0);
    STAGE(Bbase, 1, 0, 0, 0);
    STAGE(Bbase, 1, 0, 1, 0);
    STAGE(Bbase, 1, 1, 0, 1);
    STAGE(Abase, 0, 1, 0, 1);
    asm volatile("s_waitcnt vmcnt(4)" ::: "memory");
    __builtin_amdgcn_s_barrier();

#define ITER(t, LAST) do {                                                        \
    /* P1: tile t quad(Ag0,Bg0) */                                                \
    LDA(0, 0); LDB(0, 0); STAGE(Bbase, 1, 1, 1, (t) + 1);                         \
    PH_BEGIN(); MMA(0, 0); PH_END();                                              \
    /* P2: quad(Ag0,Bg1) */                                                       \
    LDB(0, 1); STAGE(Abase, 0, 1, 1, (t) + 1);                                    \
    PH_BEGIN(); MMA(0, 1); PH_END();                                              \
    /* P3: quad(Ag1,Bg1) */                                                       \
    LDA(0, 1); if (!(LAST)) STAGE(Bbase, 1, 0, 0, (t) + 2);                       \
    PH_BEGIN(); MMA(1, 1); PH_END();                                              \
    /* P4: quad(Ag1,Bg0) */                                                       \
    if (!(LAST)) STAGE(Abase, 0, 0, 0, (t) + 2);                                  \
    PH_BEGIN(); MMA(1, 0);                                                        \
    if (LAST) { PH_END_VM(0); } else { PH_END_VM(4); }                            \
    /* P5: tile t+1 quad(Ag0,Bg0) */                                              \
    LDA(1, 0); LDB(1, 0); if (!(LAST)) STAGE(Bbase, 1, 0, 1, (t) + 2);            \
    PH_BEGIN(); MMA(0, 0); PH_END();                                              \
    /* P6 */                                                                      \
    LDB(1, 1); if (!(LAST)) STAGE(Abase, 0, 0, 1, (t) + 2);                       \
    PH_BEGIN(); MMA(0, 1); PH_END();                                              \
    /* P7 */                                                                      \
    LDA(1, 1); if (!(LAST)) STAGE(Bbase, 1, 1, 0, (t) + 3);                       \
    PH_BEGIN(); MMA(1, 1); PH_END();                                              \
    /* P8 */                                                                      \
    if (!(LAST)) STAGE(Abase, 0, 1, 0, (t) + 3);                                  \
    PH_BEGIN(); MMA(1, 0);                                                        \
    if (LAST) { PH_END(); } else { PH_END_VM(4); }                                \
  } while (0)

    const int NTILES = K / BKB;   // 16
    for (int t = 0; t < NTILES - 2; t += 2) { ITER(t, false); }
    ITER(NTILES - 2, true);

    // ---- epilogue: scale, fp16-round, fp16 bias add, widen to f32 ----
    const float sx = 448.f / fmaxf(scal[0], 1e-12f);
    const float sw = 448.f / fmaxf(scal[1], 1e-12f);
    const float inv = (1.f / sx) * (1.f / sw);

    #pragma unroll
    for (int mi = 0; mi < 8; ++mi) {
        #pragma unroll
        for (int nj = 0; nj < 4; ++nj) {
            int col = bn * BN + wn * 64 + nj * 16 + r16;
            __half hb = __float2half(bias[col]);
            #pragma unroll
            for (int r = 0; r < 4; ++r) {
                int row = bm * BM + wm * 128 + mi * 16 + hi * 4 + r;
                float v = acc[mi][nj][r] * inv;
                __half h = __hadd(__float2half(v), hb);
                C[(size_t)row * N + col] = __half2float(h);
            }
        }
    }
}

extern "C" void kernel_launch(void* const* d_in, const int* in_sizes, int n_in,
                              void* d_out, int out_size, void* d_ws, size_t ws_size,
                              hipStream_t stream) {
    const float* x    = (const float*)d_in[0];
    const float* w    = (const float*)d_in[1];
    const float* bias = (const float*)d_in[2];   // fp16 in reference -> f32 on device
    float* out = (float*)d_out;

    const int N = in_sizes[2];              // 8192
    const int K = in_sizes[1] / N;          // 2048
    const int M = in_sizes[0] / K;          // 16384

    uint8_t* ws = (uint8_t*)d_ws;
    float* scal = (float*)ws;               // [0]=amax_x, [1]=amax_w
    uint8_t* Aq = ws + 256;
    uint8_t* Bq = Aq + (size_t)M * K;

    hipMemsetAsync(scal, 0, 8, stream);

    const int axb = 2048, awb = 1024;
    amax2_kernel<<<axb + awb, 256, 0, stream>>>(x, (size_t)M * K / 4,
                                                w, (size_t)N * K / 4,
                                                scal, axb, awb);

    int qxb = (int)((size_t)M * K / 16 / 256);   // 8192
    int qwb = (int)((size_t)N * K / 16 / 256);   // 4096
    quant2_kernel<<<qxb + qwb, 256, 0, stream>>>(x, w, scal,
                                                 (uint32_t*)Aq, (uint32_t*)Bq, qxb);

    dim3 grid((N / BN) * (M / BM));   // 2048
    gemm_mxfp8_8p<<<grid, 512, 0, stream>>>(Aq, Bq, scal, bias, out, M, N, K);
}

// Round 6
// 660.920 us; speedup vs baseline: 1.1445x; 1.1445x over previous
//
#include <hip/hip_runtime.h>
#include <hip/hip_fp16.h>
#include <stdint.h>
#include <stddef.h>

typedef float f32x4 __attribute__((ext_vector_type(4)));
typedef int   i32x8 __attribute__((ext_vector_type(8)));

#define GLOBAL_AS __attribute__((address_space(1)))
#define LDS_AS    __attribute__((address_space(3)))

__device__ __forceinline__ void gload_lds16(const void* g, void* l) {
    __builtin_amdgcn_global_load_lds((const GLOBAL_AS void*)g,
                                     (LDS_AS void*)l, 16, 0, 0);
}

// ---------------- fused amax (x -> scal[0], w -> scal[1]) ----------------
__global__ void amax2_kernel(const float* __restrict__ x, size_t nx4,
                             const float* __restrict__ w, size_t nw4,
                             float* __restrict__ scal, int xblocks, int wblocks) {
    int b = blockIdx.x;
    const float4* p4; size_t n4; float* out; int nb; int bb;
    if (b < xblocks) { p4 = (const float4*)x; n4 = nx4; out = scal;     nb = xblocks; bb = b; }
    else             { p4 = (const float4*)w; n4 = nw4; out = scal + 1; nb = wblocks; bb = b - xblocks; }
    float m = 0.f;
    for (size_t i = (size_t)bb * blockDim.x + threadIdx.x; i < n4;
         i += (size_t)nb * blockDim.x) {
        float4 v = p4[i];
        m = fmaxf(m, fmaxf(fmaxf(fabsf(v.x), fabsf(v.y)),
                           fmaxf(fabsf(v.z), fabsf(v.w))));
    }
    #pragma unroll
    for (int off = 32; off > 0; off >>= 1)
        m = fmaxf(m, __shfl_down(m, off, 64));
    __shared__ float sm[4];
    int wid = threadIdx.x >> 6;
    if ((threadIdx.x & 63) == 0) sm[wid] = m;
    __syncthreads();
    if (threadIdx.x == 0) {
        m = fmaxf(fmaxf(sm[0], sm[1]), fmaxf(sm[2], sm[3]));
        atomicMax((unsigned int*)out, __float_as_uint(m));
    }
}

// ---------------- fused fp8 e4m3 quantization (16 elems/thread) ----------------
__global__ void quant2_kernel(const float* __restrict__ x, const float* __restrict__ w,
                              const float* __restrict__ scal,
                              uint32_t* __restrict__ qx, uint32_t* __restrict__ qw,
                              int xblocks) {
    int b = blockIdx.x;
    const float* src; uint32_t* dst; float sc; size_t i;
    if (b < xblocks) { src = x; dst = qx; sc = 448.f / fmaxf(scal[0], 1e-12f);
                       i = (size_t)b * blockDim.x + threadIdx.x; }
    else             { src = w; dst = qw; sc = 448.f / fmaxf(scal[1], 1e-12f);
                       i = (size_t)(b - xblocks) * blockDim.x + threadIdx.x; }
    const float4* s4 = (const float4*)src + i * 4;
    uint32_t r[4];
    #pragma unroll
    for (int j = 0; j < 4; ++j) {
        float4 v = s4[j];
        uint32_t u = __builtin_amdgcn_cvt_pk_fp8_f32(v.x * sc, v.y * sc, 0u, false);
        u = __builtin_amdgcn_cvt_pk_fp8_f32(v.z * sc, v.w * sc, u, true);
        r[j] = u;
    }
    uint4 out; out.x = r[0]; out.y = r[1]; out.z = r[2]; out.w = r[3];
    *(uint4*)(dst + i * 4) = out;
}

// ---- MX-fp8 256x128 8-phase GEMM: C = A[M][K] * B[N][K]^T ----
// vs r5: per-wave output 64x64 (acc 64 regs) instead of 128x64 (128) ->
// arch-VGPR demand ~150 total, no spills. Same validated barrier discipline.
#define BM 256
#define BN 128
#define BKB 128   // K-bytes per tile

__global__ __launch_bounds__(512, 2) void gemm_mxfp8_8p2(
    const uint8_t* __restrict__ Aq,   // [M][K] fp8
    const uint8_t* __restrict__ Bq,   // [N][K] fp8
    const float* __restrict__ scal,
    const float* __restrict__ bias,   // [N] f32 (fp16-exact values)
    float* __restrict__ C,            // [M][N] f32 (fp16-rounded values)
    int M, int N, int K)
{
    __shared__ __align__(16) uint8_t ldsA[2][256 * 128];  // 64 KB
    __shared__ __align__(16) uint8_t ldsB[2][128 * 128];  // 32 KB

    const int tid  = threadIdx.x;
    const int wid  = tid >> 6;
    const int lane = tid & 63;
    const int wm = wid >> 1;           // 0..3 (row block of 64)
    const int wn = wid & 1;            // 0..1 (col block of 64)
    const int r16 = lane & 15, hi = lane >> 4;

    // XCD-aware bijective swizzle (nwg = 4096, %8 == 0)
    const int cpx = gridDim.x >> 3;
    const int sbid = (blockIdx.x & 7) * cpx + (blockIdx.x >> 3);
    const int nbn = N / BN;            // 64
    const int bn = sbid & (nbn - 1);
    const int bm = sbid / nbn;

    const uint8_t* Abase = Aq + (size_t)bm * BM * K;
    const uint8_t* Bbase = Bq + (size_t)bn * BN * K;

    // staging: one unit = 128 rows x 128 B (16 KB), 2 x 16B per thread
    const int srow = tid >> 3;                                   // 0..63
    const uint32_t soff = (uint32_t)srow * (uint32_t)K +
                          (uint32_t)(((tid & 7) ^ (srow & 7)) << 4);

    // fragment-read swizzled chunk offsets (row & 7 == r16 & 7)
    const int swz = r16 & 7;
    const int u0 = ((hi * 2)     ^ swz) << 4;
    const int u1 = ((hi * 2 + 1) ^ swz) << 4;

#define STAGE_A(bufi, h, s)                                                       \
  { const uint8_t* g_ = Abase + (uint32_t)((h) * 128 * K + (s) * BKB) + soff;     \
    uint8_t* l_ = &ldsA[bufi][(h) * 16384 + tid * 16];                            \
    gload_lds16(g_, l_);                                                          \
    gload_lds16(g_ + (uint32_t)(64 * K), l_ + 8192); }

#define STAGE_B(bufi, s)                                                          \
  { const uint8_t* g_ = Bbase + (uint32_t)((s) * BKB) + soff;                     \
    uint8_t* l_ = &ldsB[bufi][tid * 16];                                          \
    gload_lds16(g_, l_);                                                          \
    gload_lds16(g_ + (uint32_t)(64 * K), l_ + 8192); }

#define LDA(bufc, gm)                                                             \
  { _Pragma("unroll") for (int j_ = 0; j_ < 2; ++j_) {                            \
      const uint8_t* p_ = &ldsA[bufc][(wm * 64 + (gm) * 32 + j_ * 16 + r16) * 128]; \
      int4 q0_ = *(const int4*)(p_ + u0);                                         \
      int4 q1_ = *(const int4*)(p_ + u1);                                         \
      a[j_] = (i32x8){q0_.x, q0_.y, q0_.z, q0_.w, q1_.x, q1_.y, q1_.z, q1_.w}; } }

#define LDB(bufc, gn)                                                             \
  { _Pragma("unroll") for (int j_ = 0; j_ < 2; ++j_) {                            \
      const uint8_t* p_ = &ldsB[bufc][(wn * 64 + ((gn) * 2 + j_) * 16 + r16) * 128]; \
      int4 q0_ = *(const int4*)(p_ + u0);                                         \
      int4 q1_ = *(const int4*)(p_ + u1);                                         \
      b[(gn) * 2 + j_] = (i32x8){q0_.x, q0_.y, q0_.z, q0_.w, q1_.x, q1_.y, q1_.z, q1_.w}; } }

#define MMA(gm, gn)                                                               \
  __builtin_amdgcn_s_setprio(1);                                                  \
  _Pragma("unroll") for (int mi_ = 0; mi_ < 2; ++mi_)                             \
    _Pragma("unroll") for (int nj_ = 0; nj_ < 2; ++nj_)                           \
      acc[(gm) * 2 + mi_][(gn) * 2 + nj_] =                                       \
        __builtin_amdgcn_mfma_scale_f32_16x16x128_f8f6f4(                         \
          a[mi_], b[(gn) * 2 + nj_], acc[(gm) * 2 + mi_][(gn) * 2 + nj_],         \
          0, 0, 0, 0x7F7F7F7F, 0, 0x7F7F7F7F);                                    \
  __builtin_amdgcn_s_setprio(0);

#define PH_BEGIN() __builtin_amdgcn_s_barrier()
#define PH_END()   __builtin_amdgcn_s_barrier()
#define PH_END_VM(n) do { asm volatile("s_waitcnt vmcnt(" #n ")" ::: "memory");   \
    __builtin_amdgcn_s_barrier(); } while (0)

    f32x4 acc[4][4] = {};
    i32x8 a[2], b[4];

    // ---- prologue: t0 {B,A0,A1} -> buf0 ; t1 {B,A0} -> buf1 ----
    STAGE_B(0, 0);
    STAGE_A(0, 0, 0);
    STAGE_A(0, 1, 0);
    STAGE_B(1, 1);
    STAGE_A(1, 0, 1);
    asm volatile("s_waitcnt vmcnt(4)" ::: "memory");   // t0 resident
    __builtin_amdgcn_s_barrier();

    // ITER(t): computes tile t (buf0, P1-P4) and t+1 (buf1, P5-P8).
    // Stages: P1: A1(t+1)->buf1 ; P3,P4,P5: {B,A0,A1}(t+2)->buf0 ;
    //         P7,P8: {B,A0}(t+3)->buf1. vmcnt(4) at P4/P8 forces the
    //         2-units-newer FIFO: everything read next phase is resident.
#define ITER(t, LAST) do {                                                        \
    /* P1: tile t quad(0,0) */                                                    \
    LDA(0, 0); LDB(0, 0); STAGE_A(1, 1, (t) + 1);                                 \
    PH_BEGIN(); MMA(0, 0); PH_END();                                              \
    /* P2: quad(0,1) */                                                           \
    LDB(0, 1);                                                                    \
    PH_BEGIN(); MMA(0, 1); PH_END();                                              \
    /* P3: quad(1,1) */                                                           \
    LDA(0, 1); if (!(LAST)) STAGE_B(0, (t) + 2);                                  \
    PH_BEGIN(); MMA(1, 1); PH_END();                                              \
    /* P4: quad(1,0) */                                                           \
    if (!(LAST)) STAGE_A(0, 0, (t) + 2);                                          \
    PH_BEGIN(); MMA(1, 0);                                                        \
    if (LAST) { PH_END_VM(0); } else { PH_END_VM(4); }                            \
    /* P5: tile t+1 quad(0,0) */                                                  \
    LDA(1, 0); LDB(1, 0); if (!(LAST)) STAGE_A(0, 1, (t) + 2);                    \
    PH_BEGIN(); MMA(0, 0); PH_END();                                              \
    /* P6 */                                                                      \
    LDB(1, 1);                                                                    \
    PH_BEGIN(); MMA(0, 1); PH_END();                                              \
    /* P7 */                                                                      \
    LDA(1, 1); if (!(LAST)) STAGE_B(1, (t) + 3);                                  \
    PH_BEGIN(); MMA(1, 1); PH_END();                                              \
    /* P8 */                                                                      \
    if (!(LAST)) STAGE_A(1, 0, (t) + 3);                                          \
    PH_BEGIN(); MMA(1, 0);                                                        \
    if (LAST) { PH_END(); } else { PH_END_VM(4); }                                \
  } while (0)

    const int NTILES = K / BKB;   // 16
    for (int t = 0; t < NTILES - 2; t += 2) { ITER(t, false); }
    ITER(NTILES - 2, true);

    // ---- epilogue: scale, fp16-round, fp16 bias add, widen to f32 ----
    const float sx = 448.f / fmaxf(scal[0], 1e-12f);
    const float sw = 448.f / fmaxf(scal[1], 1e-12f);
    const float inv = (1.f / sx) * (1.f / sw);

    #pragma unroll
    for (int mi = 0; mi < 4; ++mi) {
        #pragma unroll
        for (int nj = 0; nj < 4; ++nj) {
            int col = bn * BN + wn * 64 + nj * 16 + r16;
            __half hb = __float2half(bias[col]);
            #pragma unroll
            for (int r = 0; r < 4; ++r) {
                int row = bm * BM + wm * 64 + mi * 16 + hi * 4 + r;
                float v = acc[mi][nj][r] * inv;
                __half h = __hadd(__float2half(v), hb);
                C[(size_t)row * N + col] = __half2float(h);
            }
        }
    }
}

extern "C" void kernel_launch(void* const* d_in, const int* in_sizes, int n_in,
                              void* d_out, int out_size, void* d_ws, size_t ws_size,
                              hipStream_t stream) {
    const float* x    = (const float*)d_in[0];
    const float* w    = (const float*)d_in[1];
    const float* bias = (const float*)d_in[2];   // fp16 in reference -> f32 on device
    float* out = (float*)d_out;

    const int N = in_sizes[2];              // 8192
    const int K = in_sizes[1] / N;          // 2048
    const int M = in_sizes[0] / K;          // 16384

    uint8_t* ws = (uint8_t*)d_ws;
    float* scal = (float*)ws;               // [0]=amax_x, [1]=amax_w
    uint8_t* Aq = ws + 256;
    uint8_t* Bq = Aq + (size_t)M * K;

    hipMemsetAsync(scal, 0, 8, stream);

    const int axb = 2048, awb = 1024;
    amax2_kernel<<<axb + awb, 256, 0, stream>>>(x, (size_t)M * K / 4,
                                                w, (size_t)N * K / 4,
                                                scal, axb, awb);

    int qxb = (int)((size_t)M * K / 16 / 256);   // 8192
    int qwb = (int)((size_t)N * K / 16 / 256);   // 4096
    quant2_kernel<<<qxb + qwb, 256, 0, stream>>>(x, w, scal,
                                                 (uint32_t*)Aq, (uint32_t*)Bq, qxb);

    dim3 grid((N / BN) * (M / BM));   // 4096
    gemm_mxfp8_8p2<<<grid, 512, 0, stream>>>(Aq, Bq, scal, bias, out, M, N, K);
}